// Round 2
// baseline (298.453 us; speedup 1.0000x reference)
//
#include <hip/hip_runtime.h>

// Problem dims
#define B_    32
#define CIN   32
#define COUT  64
#define H_    128
#define W_    128
#define HO_   126
#define WO_   126
#define MAXCN 64

typedef __attribute__((ext_vector_type(8))) short short8;
typedef __attribute__((ext_vector_type(4))) float floatx4;

static __device__ __forceinline__ unsigned short f2bf(float f) {
    union { float f; unsigned u; } v; v.f = f;
    unsigned r = v.u + 0x7fff + ((v.u >> 16) & 1);   // round-to-nearest-even
    return (unsigned short)(r >> 16);
}

// ---------------------------------------------------------------------------
// Fold masked 64-slot bank -> dense bf16 weights, FRAGMENT-ORDER layout:
//   wk[tap][quad][oc][8ch]  (chunk index = (tap*4+quad)*64 + oc, 16 B chunks)
// so conv's A-fragment load (16 lanes = 16 consecutive oc) is 256 B
// contiguous global reads. slot j feeds channel j%32, active iff j < cn[oc].
// ---------------------------------------------------------------------------
__global__ void fold_bf16(const float* __restrict__ w,
                          const int* __restrict__ cn,
                          unsigned short* __restrict__ wk) {
    int idx = blockIdx.x * 256 + threadIdx.x;        // over 9*64*32 = 18432
    if (idx >= 9 * COUT * CIN) return;
    int c   = idx & 31;
    int oc  = (idx >> 5) & 63;
    int tap = idx >> 11;
    int n = cn[oc];
    float v = 0.0f;
    if (c < n)      v += w[(oc * MAXCN + c) * 9 + tap];
    if (c + 32 < n) v += w[(oc * MAXCN + c + 32) * 9 + tap];
    wk[((tap * 4 + (c >> 3)) * 64 + oc) * 8 + (c & 7)] = f2bf(v);
}

// ---------------------------------------------------------------------------
// x [B][C][H][W] fp32 -> xb [B][H][W][C] bf16 (NHWC). LDS-free:
// thread = (pixel xi, channel-octet c8). 8 loads, each instr covers 4
// distinct 64 B cache lines (16 lanes x consecutive xi) -> full-line
// efficiency. One uint4 store; wave's 64 stores = contiguous 1024 B.
// ---------------------------------------------------------------------------
__global__ __launch_bounds__(256)
void nchw_to_nhwc_bf16(const float* __restrict__ x,
                       unsigned short* __restrict__ xb) {
    const int b = blockIdx.y, y = blockIdx.x;
    const int t = threadIdx.x;
    const int c8  = t & 3;
    const int xi0 = t >> 2;                          // 0..63
    const float* xp = x + (size_t)b * CIN * H_ * W_ + (size_t)y * W_;
#pragma unroll
    for (int it = 0; it < 2; ++it) {
        const int xi = xi0 + it * 64;
        __align__(16) unsigned short v[8];
#pragma unroll
        for (int j = 0; j < 8; ++j) {
            const int c = c8 * 8 + j;
            v[j] = f2bf(xp[(size_t)c * (H_ * W_) + xi]);
        }
        *(uint4*)(xb + (((size_t)b * H_ + y) * W_ + xi) * CIN + c8 * 8) =
            *(const uint4*)v;
    }
}

// ---------------------------------------------------------------------------
// Implicit-GEMM conv, bf16 MFMA 16x16x32.
//   Block: 16x16 pixel tile x 32 oc (ocg). 4 waves; wave w owns rows 4w..4w+3.
//   B (pixels) from LDS xs, CONFLICT-FREE layout [row][quad][x][8ch]:
//     frag read = 4 x 256 B contiguous segments at bank offsets {0,8,16,24}
//     (stride 18 chunks = 288 B -> +8 banks per quad) — exactly balanced.
//   A (weights) straight from GLOBAL in fragment order (wk is tiny, 36.8 KB,
//     read-only, shared by every block -> L1/L2-resident; 1 KB contiguous
//     per wave per load). No ws in LDS.
//   LDS = xs only, 20736 B -> 7 blocks/CU by LDS; __launch_bounds__(256,6)
//   caps VGPR at ~85 -> 6 blocks/CU = 24 waves/CU (vs 16 in round 0).
// ---------------------------------------------------------------------------
__global__ __launch_bounds__(256, 6)
void conv_mfma(const unsigned short* __restrict__ xb,
               const unsigned short* __restrict__ wk,
               const float* __restrict__ bias,
               float* __restrict__ out) {
    __shared__ __align__(16) unsigned short xs[1296 * 8];   // 20736 B

    const int tile = blockIdx.x;          // 0..63
    const int ocg  = blockIdx.y;          // 0..1
    const int b    = blockIdx.z;
    const int tx = tile & 7, ty = tile >> 3;
    const int x0 = tx * 16, y0 = ty * 16;
    const int tid = threadIdx.x;

    // ---- stage input tile: source-coalesced, dest-permuted ----
    // source chunk: pixel (yy, xc), octet cp  (xc,cp inner -> contiguous)
    // dest   chunk: (yy*4 + cp)*18 + xc       ([row][quad][x] layout)
    uint4* xs4 = (uint4*)xs;
    const uint4* xb4 = (const uint4*)(xb + (size_t)b * H_ * W_ * CIN);
#pragma unroll
    for (int k = 0; k < 5; ++k) {
        int idx = k * 256 + tid;                    // 0..1279
        int yy  = idx / 72;
        int rem = idx - yy * 72;
        int xc  = rem >> 2;
        int cp  = rem & 3;
        int iy = y0 + yy; if (iy > H_ - 1) iy = H_ - 1;
        int ix = x0 + xc; if (ix > W_ - 1) ix = W_ - 1;
        xs4[(yy * 4 + cp) * 18 + xc] = xb4[(iy * W_ + ix) * 4 + cp];
    }
    if (tid < 16) {                                 // tail chunks 1280..1295
        int idx = 1280 + tid;
        int yy  = idx / 72;
        int rem = idx - yy * 72;
        int xc  = rem >> 2;
        int cp  = rem & 3;
        int iy = y0 + yy; if (iy > H_ - 1) iy = H_ - 1;
        int ix = x0 + xc; if (ix > W_ - 1) ix = W_ - 1;
        xs4[(yy * 4 + cp) * 18 + xc] = xb4[(iy * W_ + ix) * 4 + cp];
    }
    __syncthreads();

    const int w_id = tid >> 6;
    const int lane = tid & 63;
    const int quad = lane >> 4, l16 = lane & 15;

    const short8* wq8 = (const short8*)wk;          // 16 B fragment chunks
    const int abase = quad * 64 + ocg * 32 + l16;   // + tap*256 + t*16
    const int bbase = (quad * 18 + l16) * 8;        // + row*576 + kw*8

    floatx4 acc[4][2];
#pragma unroll
    for (int i = 0; i < 4; ++i)
#pragma unroll
        for (int t = 0; t < 2; ++t) acc[i][t] = (floatx4)0.0f;

#pragma unroll
    for (int kh = 0; kh < 3; ++kh) {
#pragma unroll
        for (int kw = 0; kw < 3; ++kw) {
            const int tap = kh * 3 + kw;
            short8 a0 = wq8[tap * 256 + abase];
            short8 a1 = wq8[tap * 256 + abase + 16];
            short8 bf[4];
#pragma unroll
            for (int i = 0; i < 4; ++i)
                bf[i] = *(const short8*)&xs[(4 * w_id + i + kh) * 576 + bbase + kw * 8];
#pragma unroll
            for (int i = 0; i < 4; ++i) {
                acc[i][0] = __builtin_amdgcn_mfma_f32_16x16x32_bf16(a0, bf[i], acc[i][0], 0, 0, 0);
                acc[i][1] = __builtin_amdgcn_mfma_f32_16x16x32_bf16(a1, bf[i], acc[i][1], 0, 0, 0);
            }
        }
    }

    // ---- epilogue: +bias, guarded stores (quad-coalesced 64 B segments) ----
    const int col = x0 + l16;
    if (col < WO_) {
#pragma unroll
        for (int i = 0; i < 4; ++i) {
            const int y = y0 + 4 * w_id + i;
            if (y >= HO_) continue;
#pragma unroll
            for (int t = 0; t < 2; ++t) {
#pragma unroll
                for (int r = 0; r < 4; ++r) {
                    const int oc = ocg * 32 + t * 16 + quad * 4 + r;
                    out[(((size_t)b * COUT + oc) * HO_ + y) * WO_ + col] =
                        acc[i][t][r] + bias[((size_t)oc * HO_ + y) * WO_ + col];
                }
            }
        }
    }
}

// ===========================================================================
// Fallback fp32 path (proven in round 1) — used only if ws_size is too small
// for the 32 MiB NHWC buffer.
// ===========================================================================
__global__ void fold_kernel(const float* __restrict__ w,
                            const int* __restrict__ cn,
                            float* __restrict__ kd) {
    int idx = blockIdx.x * blockDim.x + threadIdx.x;
    if (idx >= COUT * CIN * 9) return;
    int t = idx % 9;
    int c = (idx / 9) % CIN;
    int o = idx / (9 * CIN);
    int n = cn[o];
    float v = 0.0f;
    if (c < n)      v += w[(o * MAXCN + c) * 9 + t];
    if (c + 32 < n) v += w[(o * MAXCN + c + 32) * 9 + t];
    kd[idx] = v;
}

__global__ __launch_bounds__(256)
void conv_kernel(const float* __restrict__ x,
                 const float* __restrict__ kd,
                 const float* __restrict__ bias,
                 float* __restrict__ out) {
    __shared__ __align__(16) float xsh[CIN * 18 * 20];
    __shared__ __align__(16) float wsh[16 * 289];
    const int b = blockIdx.z, ocg = blockIdx.y, tile = blockIdx.x;
    const int ty = tile >> 3, txx = tile & 7;
    const int y0 = ty * 16, x0 = txx * 16;
    const int tid = threadIdx.x;
    const float* xbp = x + (size_t)b * CIN * H_ * W_;
    for (int idx = tid; idx < CIN * 18 * 18; idx += 256) {
        int c = idx / 324, rem = idx - c * 324, r = rem / 18, col = rem - r * 18;
        int iy = y0 + r;   if (iy > H_ - 1) iy = H_ - 1;
        int ix = x0 + col; if (ix > W_ - 1) ix = W_ - 1;
        xsh[c * 360 + r * 20 + col] = xbp[(c * H_ + iy) * W_ + ix];
    }
    for (int idx = tid; idx < 16 * 288; idx += 256) {
        int oc = idx / 288, rr = idx - oc * 288;
        wsh[oc * 289 + rr] = kd[(ocg * 16 + oc) * 288 + rr];
    }
    __syncthreads();
    const int oc_l = tid & 15, pb = tid >> 4, pby = pb >> 2, pbx = pb & 3;
    float acc[4][4];
#pragma unroll
    for (int i = 0; i < 4; ++i)
#pragma unroll
        for (int j = 0; j < 4; ++j) acc[i][j] = 0.0f;
    const float* xp = &xsh[(pby * 4) * 20 + pbx * 4];
    const float* wp = &wsh[oc_l * 289];
    for (int c = 0; c < CIN; ++c) {
        float xr[6][6];
#pragma unroll
        for (int r = 0; r < 6; ++r) {
            const float* row = xp + c * 360 + r * 20;
            float4 v4 = *reinterpret_cast<const float4*>(row);
            float2 v2 = *reinterpret_cast<const float2*>(row + 4);
            xr[r][0] = v4.x; xr[r][1] = v4.y; xr[r][2] = v4.z;
            xr[r][3] = v4.w; xr[r][4] = v2.x; xr[r][5] = v2.y;
        }
        float wr[9];
#pragma unroll
        for (int t = 0; t < 9; ++t) wr[t] = wp[c * 9 + t];
#pragma unroll
        for (int kh = 0; kh < 3; ++kh)
#pragma unroll
            for (int kw = 0; kw < 3; ++kw) {
                const float wv = wr[kh * 3 + kw];
#pragma unroll
                for (int i = 0; i < 4; ++i)
#pragma unroll
                    for (int j = 0; j < 4; ++j)
                        acc[i][j] = fmaf(xr[i + kh][j + kw], wv, acc[i][j]);
            }
    }
    const int o = ocg * 16 + oc_l;
    const int yb = y0 + pby * 4, xq0 = x0 + pbx * 4;
    float* ob = out + ((size_t)(b * COUT + o)) * HO_ * WO_;
    const float* bb = bias + (size_t)o * HO_ * WO_;
#pragma unroll
    for (int i = 0; i < 4; ++i) {
        int y = yb + i;
        if (y >= HO_) continue;
#pragma unroll
        for (int j = 0; j < 4; ++j) {
            int xq = xq0 + j;
            if (xq >= WO_) continue;
            ob[y * WO_ + xq] = acc[i][j] + bb[y * WO_ + xq];
        }
    }
}

extern "C" void kernel_launch(void* const* d_in, const int* in_sizes, int n_in,
                              void* d_out, int out_size, void* d_ws, size_t ws_size,
                              hipStream_t stream) {
    const float* x    = (const float*)d_in[0];
    const float* w    = (const float*)d_in[1];
    const float* bias = (const float*)d_in[2];
    const int*   cn   = (const int*)d_in[3];
    float* out = (float*)d_out;

    const size_t XB_BYTES = (size_t)B_ * H_ * W_ * CIN * 2;   // 33554432
    const size_t WK_BYTES = (size_t)9 * COUT * CIN * 2;       // 36864

    if (ws_size >= XB_BYTES + WK_BYTES) {
        unsigned short* xbuf = (unsigned short*)d_ws;
        unsigned short* wkb  = (unsigned short*)((char*)d_ws + XB_BYTES);
        fold_bf16<<<(9 * COUT * CIN + 255) / 256, 256, 0, stream>>>(w, cn, wkb);
        nchw_to_nhwc_bf16<<<dim3(H_, B_), 256, 0, stream>>>(x, xbuf);
        conv_mfma<<<dim3(64, 2, B_), 256, 0, stream>>>(xbuf, wkb, bias, out);
    } else {
        float* kd = (float*)d_ws;                             // 73728 B
        fold_kernel<<<(COUT * CIN * 9 + 255) / 256, 256, 0, stream>>>(w, cn, kd);
        dim3 grid(64, 4, B_);
        conv_kernel<<<grid, 256, 0, stream>>>(x, kd, bias, out);
    }
}

// Round 3
// 284.488 us; speedup vs baseline: 1.0491x; 1.0491x over previous
//
#include <hip/hip_runtime.h>

// Problem dims
#define B_    32
#define CIN   32
#define COUT  64
#define H_    128
#define W_    128
#define HO_   126
#define WO_   126
#define MAXCN 64

typedef __attribute__((ext_vector_type(8))) short short8;
typedef __attribute__((ext_vector_type(4))) float floatx4;

static __device__ __forceinline__ unsigned short f2bf(float f) {
    union { float f; unsigned u; } v; v.f = f;
    unsigned r = v.u + 0x7fff + ((v.u >> 16) & 1);   // round-to-nearest-even
    return (unsigned short)(r >> 16);
}

// async global->LDS, 16 B per lane; LDS dest = wave-uniform base + lane*16
static __device__ __forceinline__ void gld16(const void* g, void* l) {
    __builtin_amdgcn_global_load_lds(
        (const __attribute__((address_space(1))) unsigned int*)g,
        (__attribute__((address_space(3))) unsigned int*)l, 16, 0, 0);
}

// ---------------------------------------------------------------------------
// Fold masked 64-slot bank -> dense bf16 weights, FRAGMENT-ORDER layout:
//   chunk index = (tap*4 + quad)*64 + oc   (16 B chunks of 8 channels)
// slot j feeds channel j%32, active iff j < cn[oc].
// ---------------------------------------------------------------------------
__global__ void fold_bf16(const float* __restrict__ w,
                          const int* __restrict__ cn,
                          unsigned short* __restrict__ wk) {
    int idx = blockIdx.x * 256 + threadIdx.x;        // over 9*64*32 = 18432
    if (idx >= 9 * COUT * CIN) return;
    int c   = idx & 31;
    int oc  = (idx >> 5) & 63;
    int tap = idx >> 11;
    int n = cn[oc];
    float v = 0.0f;
    if (c < n)      v += w[(oc * MAXCN + c) * 9 + tap];
    if (c + 32 < n) v += w[(oc * MAXCN + c + 32) * 9 + tap];
    wk[((tap * 4 + (c >> 3)) * 64 + oc) * 8 + (c & 7)] = f2bf(v);
}

// ---------------------------------------------------------------------------
// x [B][C][H][W] fp32 -> xb [B][H][W][C] bf16 (NHWC).
// ---------------------------------------------------------------------------
__global__ __launch_bounds__(256)
void nchw_to_nhwc_bf16(const float* __restrict__ x,
                       unsigned short* __restrict__ xb) {
    const int b = blockIdx.y, y = blockIdx.x;
    const int t = threadIdx.x;
    const int c8  = t & 3;
    const int xi0 = t >> 2;                          // 0..63
    const float* xp = x + (size_t)b * CIN * H_ * W_ + (size_t)y * W_;
#pragma unroll
    for (int it = 0; it < 2; ++it) {
        const int xi = xi0 + it * 64;
        __align__(16) unsigned short v[8];
#pragma unroll
        for (int j = 0; j < 8; ++j) {
            const int c = c8 * 8 + j;
            v[j] = f2bf(xp[(size_t)c * (H_ * W_) + xi]);
        }
        *(uint4*)(xb + (((size_t)b * H_ + y) * W_ + xi) * CIN + c8 * 8) =
            *(const uint4*)v;
    }
}

// ---------------------------------------------------------------------------
// bias [oc][y][x] -> bnhwc [y][x][oc]  (float4-loadable epilogue bias)
// grid 3969*256 == 126*126*64 exactly.
// ---------------------------------------------------------------------------
__global__ __launch_bounds__(256)
void bias_to_nhwc(const float* __restrict__ bias, float* __restrict__ bn) {
    int idx = blockIdx.x * 256 + threadIdx.x;
    int oc = idx & 63;
    int p  = idx >> 6;
    int y  = p / WO_;
    int x  = p - y * WO_;
    bn[idx] = bias[((size_t)oc * HO_ + y) * WO_ + x];
}

// ---------------------------------------------------------------------------
// Stage one 18x18-pixel input tile (1296 16 B chunks) into LDS buffer bsel.
// LDS dest LINEAR in chunk index d; global source is the INVERSE permutation
// of the conflict-free read layout  d = (row*4 + cp)*18 + xc  (m173 pattern).
// Each wave covers chunks [w*324, (w+1)*324): 5 full gld16 calls + 4-lane tail.
// ---------------------------------------------------------------------------
static __device__ __forceinline__
void stage_tile(const unsigned short* __restrict__ xbi,
                unsigned short* __restrict__ lds,
                int w_id, int lane, int y0, int x0, int bsel) {
    unsigned short* dst = lds + bsel * (1296 * 8);
#pragma unroll
    for (int k = 0; k < 5; ++k) {
        const int base = w_id * 324 + k * 64;
        const int d = base + lane;
        const int q = d / 18, xc = d - q * 18;
        const int row = q >> 2, cp = q & 3;
        int iy = y0 + row; if (iy > H_ - 1) iy = H_ - 1;
        int ix = x0 + xc;  if (ix > W_ - 1) ix = W_ - 1;
        gld16(xbi + (((iy << 7) + ix) * 4 + cp) * 8, dst + base * 8);
    }
    {
        const int base = w_id * 324 + 320;
        if (lane < 4) {
            const int d = base + lane;
            const int q = d / 18, xc = d - q * 18;
            const int row = q >> 2, cp = q & 3;
            int iy = y0 + row; if (iy > H_ - 1) iy = H_ - 1;
            int ix = x0 + xc;  if (ix > W_ - 1) ix = W_ - 1;
            gld16(xbi + (((iy << 7) + ix) * 4 + cp) * 8, dst + base * 8);
        }
    }
}

// ---------------------------------------------------------------------------
// Pipelined implicit-GEMM conv, bf16 MFMA 16x16x32.
//   Block = 4-tile row strip (16 rows x 64 cols) x ALL 64 oc. 4 waves; wave w
//   owns output rows 4w..4w+3 of each tile. Grid 512 = exactly 2 blocks/CU.
//   LDS 78336 B: xs double buffer 2x20736 + ws 36864 (weights staged ONCE
//   per block, amortized over 4 tiles; both MFMA operands from LDS — R1/R2
//   proved global-operand inner loops miss cache under streaming).
//   2-phase pipeline: issue global_load_lds stage of tile t+1, compute tile
//   t from the other buffer, epilogue, one __syncthreads (vmcnt drain) per
//   tile. HBM stays busy during compute; stage latency hides under MFMA.
//   Conflict-free LDS reads: B frag = 4 quads at bank offsets {0,8,16,24},
//   16 lanes contiguous 256 B each; A frag = per-quad full bank sweeps.
// ---------------------------------------------------------------------------
__global__ __launch_bounds__(256)
void conv_mfma(const unsigned short* __restrict__ xb,
               const unsigned short* __restrict__ wk,
               const float* __restrict__ bnhwc,
               float* __restrict__ out) {
    __shared__ __align__(16) unsigned short lds[4896 * 8];   // 78336 B

    const int s   = blockIdx.x;           // 0..511
    const int img = s >> 4;
    const int ty  = (s >> 1) & 7;
    const int tx0 = (s & 1) * 4;
    const int y0  = ty * 16;
    const int tid = threadIdx.x;
    const int w_id = tid >> 6, lane = tid & 63;
    const int quad = lane >> 4, l16 = lane & 15;

    const unsigned short* xbi = xb + (size_t)img * (H_ * W_ * CIN);

    // ---- stage all 64-oc weights once: 2304 chunks, identity mapping ----
#pragma unroll
    for (int k = 0; k < 9; ++k) {
        const int ch = w_id * 576 + k * 64;
        gld16(wk + (ch + lane) * 8, &lds[(2592 + ch) * 8]);
    }
    // ---- stage first tile into buffer 0 ----
    stage_tile(xbi, lds, w_id, lane, y0, tx0 * 16, 0);
    __syncthreads();

    for (int t = 0; t < 4; ++t) {
        const int buf = t & 1;
        if (t < 3)
            stage_tile(xbi, lds, w_id, lane, y0, (tx0 + t + 1) * 16, buf ^ 1);

        const unsigned short* xsb = lds + buf * (1296 * 8);
        const unsigned short* wsb = lds + 2592 * 8;

        floatx4 acc[4][4];
#pragma unroll
        for (int i = 0; i < 4; ++i)
#pragma unroll
            for (int tt = 0; tt < 4; ++tt) acc[i][tt] = (floatx4)0.0f;

#pragma unroll
        for (int kh = 0; kh < 3; ++kh) {
#pragma unroll
            for (int kw = 0; kw < 3; ++kw) {
                const int tap = kh * 3 + kw;
                short8 a[4], bf[4];
#pragma unroll
                for (int tt = 0; tt < 4; ++tt)
                    a[tt] = *(const short8*)&wsb[((tap * 4 + quad) * 64 + tt * 16 + l16) * 8];
#pragma unroll
                for (int i = 0; i < 4; ++i)
                    bf[i] = *(const short8*)&xsb[(((4 * w_id + i + kh) * 4 + quad) * 18 + l16 + kw) * 8];
#pragma unroll
                for (int i = 0; i < 4; ++i)
#pragma unroll
                    for (int tt = 0; tt < 4; ++tt)
                        acc[i][tt] = __builtin_amdgcn_mfma_f32_16x16x32_bf16(a[tt], bf[i], acc[i][tt], 0, 0, 0);
            }
        }

        // ---- epilogue: float4 NHWC bias + guarded quad-coalesced stores ----
        const int col = (tx0 + t) * 16 + l16;
        if (col < WO_) {
#pragma unroll
            for (int i = 0; i < 4; ++i) {
                const int y = y0 + 4 * w_id + i;
                if (y >= HO_) continue;
                const float* bp = bnhwc + ((size_t)y * WO_ + col) * COUT;
#pragma unroll
                for (int tt = 0; tt < 4; ++tt) {
                    const float4 bv = *(const float4*)(bp + tt * 16 + quad * 4);
#pragma unroll
                    for (int r = 0; r < 4; ++r) {
                        const int oc = tt * 16 + quad * 4 + r;
                        out[(((size_t)(img * COUT + oc)) * HO_ + y) * WO_ + col] =
                            acc[i][tt][r] + bv[r];
                    }
                }
            }
        }
        if (t < 3) __syncthreads();
    }
}

// ===========================================================================
// Fallback fp32 path — used only if ws_size is too small.
// ===========================================================================
__global__ void fold_kernel(const float* __restrict__ w,
                            const int* __restrict__ cn,
                            float* __restrict__ kd) {
    int idx = blockIdx.x * blockDim.x + threadIdx.x;
    if (idx >= COUT * CIN * 9) return;
    int t = idx % 9;
    int c = (idx / 9) % CIN;
    int o = idx / (9 * CIN);
    int n = cn[o];
    float v = 0.0f;
    if (c < n)      v += w[(o * MAXCN + c) * 9 + t];
    if (c + 32 < n) v += w[(o * MAXCN + c + 32) * 9 + t];
    kd[idx] = v;
}

__global__ __launch_bounds__(256)
void conv_kernel(const float* __restrict__ x,
                 const float* __restrict__ kd,
                 const float* __restrict__ bias,
                 float* __restrict__ out) {
    __shared__ __align__(16) float xsh[CIN * 18 * 20];
    __shared__ __align__(16) float wsh[16 * 289];
    const int b = blockIdx.z, ocg = blockIdx.y, tile = blockIdx.x;
    const int ty = tile >> 3, txx = tile & 7;
    const int y0 = ty * 16, x0 = txx * 16;
    const int tid = threadIdx.x;
    const float* xbp = x + (size_t)b * CIN * H_ * W_;
    for (int idx = tid; idx < CIN * 18 * 18; idx += 256) {
        int c = idx / 324, rem = idx - c * 324, r = rem / 18, col = rem - r * 18;
        int iy = y0 + r;   if (iy > H_ - 1) iy = H_ - 1;
        int ix = x0 + col; if (ix > W_ - 1) ix = W_ - 1;
        xsh[c * 360 + r * 20 + col] = xbp[(c * H_ + iy) * W_ + ix];
    }
    for (int idx = tid; idx < 16 * 288; idx += 256) {
        int oc = idx / 288, rr = idx - oc * 288;
        wsh[oc * 289 + rr] = kd[(ocg * 16 + oc) * 288 + rr];
    }
    __syncthreads();
    const int oc_l = tid & 15, pb = tid >> 4, pby = pb >> 2, pbx = pb & 3;
    float acc[4][4];
#pragma unroll
    for (int i = 0; i < 4; ++i)
#pragma unroll
        for (int j = 0; j < 4; ++j) acc[i][j] = 0.0f;
    const float* xp = &xsh[(pby * 4) * 20 + pbx * 4];
    const float* wp = &wsh[oc_l * 289];
    for (int c = 0; c < CIN; ++c) {
        float xr[6][6];
#pragma unroll
        for (int r = 0; r < 6; ++r) {
            const float* row = xp + c * 360 + r * 20;
            float4 v4 = *reinterpret_cast<const float4*>(row);
            float2 v2 = *reinterpret_cast<const float2*>(row + 4);
            xr[r][0] = v4.x; xr[r][1] = v4.y; xr[r][2] = v4.z;
            xr[r][3] = v4.w; xr[r][4] = v2.x; xr[r][5] = v2.y;
        }
        float wr[9];
#pragma unroll
        for (int t = 0; t < 9; ++t) wr[t] = wp[c * 9 + t];
#pragma unroll
        for (int kh = 0; kh < 3; ++kh)
#pragma unroll
            for (int kw = 0; kw < 3; ++kw) {
                const float wv = wr[kh * 3 + kw];
#pragma unroll
                for (int i = 0; i < 4; ++i)
#pragma unroll
                    for (int j = 0; j < 4; ++j)
                        acc[i][j] = fmaf(xr[i + kh][j + kw], wv, acc[i][j]);
            }
    }
    const int o = ocg * 16 + oc_l;
    const int yb = y0 + pby * 4, xq0 = x0 + pbx * 4;
    float* ob = out + ((size_t)(b * COUT + o)) * HO_ * WO_;
    const float* bb = bias + (size_t)o * HO_ * WO_;
#pragma unroll
    for (int i = 0; i < 4; ++i) {
        int y = yb + i;
        if (y >= HO_) continue;
#pragma unroll
        for (int j = 0; j < 4; ++j) {
            int xq = xq0 + j;
            if (xq >= WO_) continue;
            ob[y * WO_ + xq] = acc[i][j] + bb[y * WO_ + xq];
        }
    }
}

extern "C" void kernel_launch(void* const* d_in, const int* in_sizes, int n_in,
                              void* d_out, int out_size, void* d_ws, size_t ws_size,
                              hipStream_t stream) {
    const float* x    = (const float*)d_in[0];
    const float* w    = (const float*)d_in[1];
    const float* bias = (const float*)d_in[2];
    const int*   cn   = (const int*)d_in[3];
    float* out = (float*)d_out;

    const size_t XB_BYTES = (size_t)B_ * H_ * W_ * CIN * 2;   // 33554432
    const size_t WK_BYTES = (size_t)9 * COUT * CIN * 2;       // 36864
    const size_t BN_BYTES = (size_t)HO_ * WO_ * COUT * 4;     // 4064256

    if (ws_size >= XB_BYTES + WK_BYTES + BN_BYTES) {
        unsigned short* xbuf = (unsigned short*)d_ws;
        unsigned short* wkb  = (unsigned short*)((char*)d_ws + XB_BYTES);
        float*          bnb  = (float*)((char*)d_ws + XB_BYTES + WK_BYTES);
        fold_bf16<<<72, 256, 0, stream>>>(w, cn, wkb);
        nchw_to_nhwc_bf16<<<dim3(H_, B_), 256, 0, stream>>>(x, xbuf);
        bias_to_nhwc<<<3969, 256, 0, stream>>>(bias, bnb);
        conv_mfma<<<512, 256, 0, stream>>>(xbuf, wkb, bnb, out);
    } else {
        float* kd = (float*)d_ws;                             // 73728 B
        fold_kernel<<<(COUT * CIN * 9 + 255) / 256, 256, 0, stream>>>(w, cn, kd);
        dim3 grid(64, 4, B_);
        conv_kernel<<<grid, 256, 0, stream>>>(x, kd, bias, out);
    }
}